// Round 8
// baseline (247.393 us; speedup 1.0000x reference)
//
#include <hip/hip_runtime.h>
#include <stdint.h>

// Problem constants
#define SEQ   4096
#define DIMM  512
#define HDIM  64
#define NH    8
#define ROWS  8192          // B*N = 2*4096
#define QKVN  1536          // 3*DIM

typedef __attribute__((ext_vector_type(8))) __bf16 bf16x8;   // MFMA A/B frag (4 VGPRs)
typedef __attribute__((ext_vector_type(4))) float  f32x4;    // MFMA C/D frag
typedef __attribute__((ext_vector_type(2))) uint32_t u32x2;

// fp32 -> bf16 (RNE), storage as uint16_t bit pattern
__device__ __forceinline__ uint16_t f2bfu(float f) {
  uint32_t u = __builtin_bit_cast(uint32_t, f);
  return (uint16_t)((u + 0x7FFFu + ((u >> 16) & 1u)) >> 16);
}

__device__ __forceinline__ f32x4 mfma16(bf16x8 a, bf16x8 b, f32x4 c) {
  return __builtin_amdgcn_mfma_f32_16x16x32_bf16(a, b, c, 0, 0, 0);
}

#if __has_builtin(__builtin_amdgcn_exp2f)
#define EXP2F(x) __builtin_amdgcn_exp2f(x)
#else
#define EXP2F(x) exp2f(x)
#endif

// async global->LDS, 16B per lane. LDS dest is wave-uniform base + lane*16;
// the GLOBAL address is per-lane free -> we use it to store XOR-swizzled tiles.
__device__ __forceinline__ void gld16(const void* g, void* l) {
  __builtin_amdgcn_global_load_lds(
      (const __attribute__((address_space(1))) uint32_t*)g,
      (__attribute__((address_space(3))) uint32_t*)l, 16, 0, 0);
}

// ---------------------------------------------------------------------------
// Kernel 1: fp32 -> bf16 conversion of x, w_qkv, w_proj (one grid, 3 segments)
// ---------------------------------------------------------------------------
#define X4  (ROWS * DIMM / 4)    // 1048576
#define Q4  (QKVN * DIMM / 4)    // 196608
#define P4  (DIMM * DIMM / 4)    // 65536

__global__ __launch_bounds__(256) void cvt_kernel(
    const float* __restrict__ x, const float* __restrict__ wq,
    const float* __restrict__ wp, uint16_t* __restrict__ xb,
    uint16_t* __restrict__ wqb, uint16_t* __restrict__ wpb) {
  int idx = blockIdx.x * 256 + threadIdx.x;    // float4 index
  const float* src; uint16_t* dst; int i4;
  if (idx < X4)            { src = x;  dst = xb;  i4 = idx; }
  else if (idx < X4 + Q4)  { src = wq; dst = wqb; i4 = idx - X4; }
  else                     { src = wp; dst = wpb; i4 = idx - X4 - Q4; }
  float4 v = ((const float4*)src)[i4];
  ushort4 o;
  o.x = f2bfu(v.x); o.y = f2bfu(v.y); o.z = f2bfu(v.z); o.w = f2bfu(v.w);
  ((ushort4*)dst)[i4] = o;
}

// ---------------------------------------------------------------------------
// Shared GEMM core: C[128x128] = A[128xK] * B[128xK]^T  (both row-major, K=512)
// 256 threads = 4 waves in 2x2, each wave 64x64 via 4x4 MFMA frags.
// acc[i][j] frag: C[row = A-row][col = B-row]. Orientation (C vs C^T) is chosen
// by which operand is passed as A.
// ---------------------------------------------------------------------------
__device__ __forceinline__ void gemm_core(
    const uint16_t* __restrict__ A, const uint16_t* __restrict__ B,
    uint16_t* As, uint16_t* Bs, f32x4 acc[4][4]) {
  const int tid = threadIdx.x;
  const int lane = tid & 63, wave = tid >> 6;
  const int quad = lane >> 4, l16 = lane & 15;
  const int wr = (wave & 1) * 64, wc = (wave >> 1) * 64;
  const int bm = blockIdx.x, bn = blockIdx.y;
  const int sw = (l16 >> 1) & 3;               // read-side swizzle key

  for (int kt = 0; kt < DIMM / 32; ++kt) {
#pragma unroll
    for (int it = 0; it < 2; ++it) {
      int L = it * 256 + tid;
      int r = L >> 2, c = L & 3;
      int gc = c ^ ((r >> 1) & 3);
      int ldsoff = (it * 256 + (tid & ~63)) * 16; // wave-uniform base
      gld16((const char*)A + ((size_t)(bm * 128 + r) * DIMM + kt * 32) * 2 + gc * 16,
            (char*)As + ldsoff);
      gld16((const char*)B + ((size_t)(bn * 128 + r) * DIMM + kt * 32) * 2 + gc * 16,
            (char*)Bs + ldsoff);
    }
    __syncthreads();
    bf16x8 af[4], bfr[4];
#pragma unroll
    for (int i = 0; i < 4; ++i)
      af[i] = *(const bf16x8*)(As + (wr + i * 16 + l16) * 32 + ((quad ^ sw) * 8));
#pragma unroll
    for (int j = 0; j < 4; ++j)
      bfr[j] = *(const bf16x8*)(Bs + (wc + j * 16 + l16) * 32 + ((quad ^ sw) * 8));
#pragma unroll
    for (int i = 0; i < 4; ++i)
#pragma unroll
      for (int j = 0; j < 4; ++j)
        acc[i][j] = mfma16(af[i], bfr[j], acc[i][j]);
    __syncthreads();
  }
}

// ---------------------------------------------------------------------------
// Kernel 2a: QK GEMM in C^T orientation: C^T[jc][m] = W_qk · X^T.
// Lane's 4 acc regs = 4 consecutive jc (= consecutive hd) -> ushort4 stores.
//   q: [bh][n][64] bf16, pre-scaled by 0.125*log2(e); k: [bh][n][64] bf16
// Grid (8, 64): bm over jc-tiles (rows 0..1023 of w_qkv), bn over m-tiles.
// ---------------------------------------------------------------------------
__global__ __launch_bounds__(256, 2) void qk_gemm(
    const uint16_t* __restrict__ xb, const uint16_t* __restrict__ wqb,
    uint16_t* __restrict__ qd, uint16_t* __restrict__ kd) {
  __shared__ __align__(16) uint16_t As[128 * 32];
  __shared__ __align__(16) uint16_t Bs[128 * 32];
  f32x4 acc[4][4];
#pragma unroll
  for (int i = 0; i < 4; ++i)
#pragma unroll
    for (int j = 0; j < 4; ++j) acc[i][j] = f32x4{0.f, 0.f, 0.f, 0.f};

  gemm_core(wqb, xb, As, Bs, acc);    // A = weights -> acc rows are jc

  const int lane = threadIdx.x & 63, wave = threadIdx.x >> 6;
  const int quad = lane >> 4, l16 = lane & 15;
  const int wr = (wave & 1) * 64, wc = (wave >> 1) * 64;
  const float qscale = 0.125f * 1.44269504f;   // fold log2(e) for exp2 softmax
  const bool isq = (blockIdx.x < 4);           // jc < 512 -> q (uniform per block)
  uint16_t* dst = isq ? qd : kd;
  const float s = isq ? qscale : 1.0f;
#pragma unroll
  for (int i = 0; i < 4; ++i) {
    int jc0 = blockIdx.x * 128 + wr + i * 16 + quad * 4;  // 4 consecutive jc
    int h = (jc0 >> 6) & 7, hd = jc0 & 63;                // hd % 4 == 0
#pragma unroll
    for (int j = 0; j < 4; ++j) {
      int m = blockIdx.y * 128 + wc + j * 16 + l16;
      int b = m >> 12, n = m & 4095;
      int bh = (b << 3) | h;
      ushort4 pk;
      pk.x = f2bfu(acc[i][j][0] * s); pk.y = f2bfu(acc[i][j][1] * s);
      pk.z = f2bfu(acc[i][j][2] * s); pk.w = f2bfu(acc[i][j][3] * s);
      *(ushort4*)(dst + ((size_t)bh * SEQ + n) * HDIM + hd) = pk;
    }
  }
}

// ---------------------------------------------------------------------------
// Kernel 2b: V GEMM, normal orientation (lane's 4 regs = 4 consecutive n ->
// ushort4 into transposed vt). Grid (64, 4): bm over m, bn over v-cols.
//   v: stored TRANSPOSED [bh][64][n] bf16
// ---------------------------------------------------------------------------
__global__ __launch_bounds__(256, 2) void v_gemm(
    const uint16_t* __restrict__ xb, const uint16_t* __restrict__ wvb,
    uint16_t* __restrict__ vt) {
  __shared__ __align__(16) uint16_t As[128 * 32];
  __shared__ __align__(16) uint16_t Bs[128 * 32];
  f32x4 acc[4][4];
#pragma unroll
  for (int i = 0; i < 4; ++i)
#pragma unroll
    for (int j = 0; j < 4; ++j) acc[i][j] = f32x4{0.f, 0.f, 0.f, 0.f};

  gemm_core(xb, wvb, As, Bs, acc);    // A = x -> acc rows are m

  const int lane = threadIdx.x & 63, wave = threadIdx.x >> 6;
  const int quad = lane >> 4, l16 = lane & 15;
  const int wr = (wave & 1) * 64, wc = (wave >> 1) * 64;
#pragma unroll
  for (int i = 0; i < 4; ++i) {
    int m0 = blockIdx.x * 128 + wr + i * 16 + quad * 4;  // 4 consecutive n
    int b = m0 >> 12, n0 = m0 & 4095;
#pragma unroll
    for (int j = 0; j < 4; ++j) {
      int jcl = blockIdx.y * 128 + wc + j * 16 + l16;    // 0..511 within v region
      int h = (jcl >> 6) & 7, hd = jcl & 63;
      int bh = (b << 3) | h;
      ushort4 pk;
      pk.x = f2bfu(acc[i][j][0]); pk.y = f2bfu(acc[i][j][1]);
      pk.z = f2bfu(acc[i][j][2]); pk.w = f2bfu(acc[i][j][3]);
      *(ushort4*)(vt + ((size_t)bh * HDIM + hd) * SEQ + n0) = pk;
    }
  }
}

// ---------------------------------------------------------------------------
// Kernel 3: flash attention, S^T formulation, key-split wave pairs.
// R8: K read DIRECTLY from global (L2-resident after XCD swizzle) -- no Ks
// staging, no K LDS reads. LDS holds only Vs (staged) + per-wave Ps.
// 1D grid 512: bh = blk & 15, qt = blk >> 4 -> all 32 blocks of a bh land on
// one XCD (round-robin dispatch heuristic; perf-only, correctness-neutral).
// 512 threads = 8 waves; pair = wave>>1 owns 32 q-rows; khalf = wave&1 takes
// 64 of each 128-key tile.
// LDS = Vs 16K + Ps 32K + Lb = 48.5K -> 2 blocks/CU, 16 waves/CU.
// ---------------------------------------------------------------------------
__global__ __launch_bounds__(512, 4) void attn_kernel(
    const uint16_t* __restrict__ qd, const uint16_t* __restrict__ kd,
    const uint16_t* __restrict__ vt, uint16_t* __restrict__ ao) {
  __shared__ __align__(16) uint16_t Vs[64 * 128];    // [d][key], chunk c^=(row&15)
  __shared__ __align__(16) uint16_t Ps[8][32 * 64];  // per-wave [q32][key64], 4KB each
  __shared__ __align__(16) float2 Lb[4 * 64];        // pair-merge lsum buffer

  const int tid = threadIdx.x, lane = tid & 63, wave = tid >> 6;  // wave 0..7
  const int quad = lane >> 4, l16 = lane & 15;
  const int pair = wave >> 1, khalf = wave & 1;
  const int qt = blockIdx.x >> 4, bh = blockIdx.x & 15;   // XCD-local bh
  const size_t base_qk = (size_t)bh * SEQ * HDIM;    // [bh][n][d]
  const size_t base_v  = (size_t)bh * HDIM * SEQ;    // [bh][d][n]
  const int sw7 = l16 & 7;
  char* Pw = (char*)Ps + wave * 4096;

  // Q fragments straight from global (one-time, L2-resident): B-op of K·Q^T
  bf16x8 qf[2][2];
#pragma unroll
  for (int it2 = 0; it2 < 2; ++it2)
#pragma unroll
    for (int kh = 0; kh < 2; ++kh)
      qf[it2][kh] = *(const bf16x8*)(qd + base_qk +
          (size_t)(qt * 128 + pair * 32 + it2 * 16 + l16) * HDIM + kh * 32 + quad * 8);

  f32x4 O[2][4];            // partial over this wave's keys
  float lsum[2] = {0.f, 0.f};
#pragma unroll
  for (int a = 0; a < 2; ++a)
#pragma unroll
    for (int d = 0; d < 4; ++d) O[a][d] = f32x4{0.f, 0.f, 0.f, 0.f};

  for (int kt = 0; kt < SEQ / 128; ++kt) {
    // stage Vt [64][128] only (16KB = 1024 chunks, 2 per thread), chunk-swizzled
#pragma unroll
    for (int it = 0; it < 2; ++it) {
      int L = it * 512 + tid;
      int ldsoff = (it * 512 + (tid & ~63)) * 16;
      int rv = L >> 4, cv = L & 15;
      int gcv = cv ^ (rv & 15);
      gld16((const char*)vt + (base_v + (size_t)rv * SEQ + (size_t)kt * 128) * 2 + gcv * 16,
            (char*)Vs + ldsoff);
    }
    __syncthreads();

    // S^T = K·Q^T for this wave's 64 keys; K A-frags DIRECT from global (L2)
    f32x4 P[4][2];
#pragma unroll
    for (int jh = 0; jh < 4; ++jh) {
      int jf = khalf * 4 + jh;
      const uint16_t* krow = kd + base_qk +
          (size_t)(kt * 128 + jf * 16 + l16) * HDIM;
      bf16x8 kf0 = *(const bf16x8*)(krow + quad * 8);
      bf16x8 kf1 = *(const bf16x8*)(krow + 32 + quad * 8);
#pragma unroll
      for (int it2 = 0; it2 < 2; ++it2) {
        f32x4 s = f32x4{0.f, 0.f, 0.f, 0.f};
        s = mfma16(kf0, qf[it2][0], s);
        s = mfma16(kf1, qf[it2][1], s);
        P[jh][it2] = s;
      }
    }

    // exp2, per-lane l partials, pack 4 consecutive keys -> one b64 LDS write
#pragma unroll
    for (int jh = 0; jh < 4; ++jh)
#pragma unroll
      for (int it2 = 0; it2 < 2; ++it2) {
        float p0 = EXP2F(P[jh][it2][0]);
        float p1 = EXP2F(P[jh][it2][1]);
        float p2 = EXP2F(P[jh][it2][2]);
        float p3 = EXP2F(P[jh][it2][3]);
        lsum[it2] += (p0 + p1) + (p2 + p3);
        uint32_t a0 = __builtin_bit_cast(uint32_t, p0) + 0x8000u;
        uint32_t a1 = __builtin_bit_cast(uint32_t, p1) + 0x8000u;
        uint32_t a2 = __builtin_bit_cast(uint32_t, p2) + 0x8000u;
        uint32_t a3 = __builtin_bit_cast(uint32_t, p3) + 0x8000u;
        u32x2 pk;
        pk.x = (a0 >> 16) | (a1 & 0xFFFF0000u);   // [bf16(p0), bf16(p1)]
        pk.y = (a2 >> 16) | (a3 & 0xFFFF0000u);   // [bf16(p2), bf16(p3)]
        int c16 = (jh * 2 + (quad >> 1)) ^ sw7;
        *(u32x2*)(Pw + (it2 * 16 + l16) * 128 + c16 * 16 + (quad & 1) * 8) = pk;
      }

    // O^T += V^T·P^T over this wave's 64 keys (2 blocks of K=32)
#pragma unroll
    for (int kp = 0; kp < 2; ++kp) {
      bf16x8 pb[2];
#pragma unroll
      for (int it2 = 0; it2 < 2; ++it2)
        pb[it2] = *(const bf16x8*)(Pw + (it2 * 16 + l16) * 128 +
                                   (((kp * 4 + quad) ^ sw7) * 16));
      bf16x8 va[4];
#pragma unroll
      for (int dl = 0; dl < 4; ++dl)
        va[dl] = *(const bf16x8*)((const char*)Vs + (dl * 16 + l16) * 256 +
                                  (((khalf * 8 + kp * 4 + quad) ^ l16) & 15) * 16);
#pragma unroll
      for (int it2 = 0; it2 < 2; ++it2)
#pragma unroll
        for (int dl = 0; dl < 4; ++dl)
          O[it2][dl] = mfma16(va[dl], pb[it2], O[it2][dl]);
    }
    __syncthreads();
  }

  // merge partial O / lsum across the wave pair (even wave -> LDS, odd reads)
  if (!(wave & 1)) {
    f32x4* ob = (f32x4*)((char*)Ps + wave * 4096);   // 8KB: Ps[wave]+Ps[wave+1]
#pragma unroll
    for (int it2 = 0; it2 < 2; ++it2)
#pragma unroll
      for (int dl = 0; dl < 4; ++dl)
        ob[(it2 * 4 + dl) * 64 + lane] = O[it2][dl];
    Lb[pair * 64 + lane] = make_float2(lsum[0], lsum[1]);
  }
  __syncthreads();
  if (wave & 1) {
    const f32x4* ob = (const f32x4*)((char*)Ps + (wave - 1) * 4096);
    float2 lp = Lb[pair * 64 + lane];
    lsum[0] += lp.x; lsum[1] += lp.y;
#pragma unroll
    for (int it2 = 0; it2 < 2; ++it2)
#pragma unroll
      for (int dl = 0; dl < 4; ++dl)
        O[it2][dl] += ob[(it2 * 4 + dl) * 64 + lane];

    const int b = bh >> 3, h = bh & 7;
#pragma unroll
    for (int it2 = 0; it2 < 2; ++it2) {
      float l = lsum[it2];
      l += __shfl_xor(l, 16);
      l += __shfl_xor(l, 32);
      float inv = 1.0f / l;
      int q = qt * 128 + pair * 32 + it2 * 16 + l16;
      size_t rowbase = ((size_t)(b * SEQ + q)) * DIMM + h * HDIM;
#pragma unroll
      for (int dl = 0; dl < 4; ++dl) {
        ushort4 pk;
        pk.x = f2bfu(O[it2][dl][0] * inv);
        pk.y = f2bfu(O[it2][dl][1] * inv);
        pk.z = f2bfu(O[it2][dl][2] * inv);
        pk.w = f2bfu(O[it2][dl][3] * inv);
        *(ushort4*)(ao + rowbase + dl * 16 + quad * 4) = pk;
      }
    }
  }
}

// ---------------------------------------------------------------------------
// Kernel 4: output projection in C^T orientation: C^T[jc][m] = W_p · AO^T.
// Lane's 4 regs = 4 consecutive out-cols -> float4 store with float4 bias.
// Grid (4, 64).
// ---------------------------------------------------------------------------
__global__ __launch_bounds__(256, 2) void proj_gemm(
    const uint16_t* __restrict__ ao, const uint16_t* __restrict__ wpb,
    const float* __restrict__ bprj, float* __restrict__ out) {
  __shared__ __align__(16) uint16_t As[128 * 32];
  __shared__ __align__(16) uint16_t Bs[128 * 32];
  f32x4 acc[4][4];
#pragma unroll
  for (int i = 0; i < 4; ++i)
#pragma unroll
    for (int j = 0; j < 4; ++j) acc[i][j] = f32x4{0.f, 0.f, 0.f, 0.f};

  gemm_core(wpb, ao, As, Bs, acc);    // A = weights -> acc rows are jc

  const int lane = threadIdx.x & 63, wave = threadIdx.x >> 6;
  const int quad = lane >> 4, l16 = lane & 15;
  const int wr = (wave & 1) * 64, wc = (wave >> 1) * 64;
#pragma unroll
  for (int i = 0; i < 4; ++i) {
    int jc0 = blockIdx.x * 128 + wr + i * 16 + quad * 4;  // 4 consecutive cols
    float4 b4 = *(const float4*)(bprj + jc0);
#pragma unroll
    for (int j = 0; j < 4; ++j) {
      int m = blockIdx.y * 128 + wc + j * 16 + l16;
      float4 o;
      o.x = acc[i][j][0] + b4.x; o.y = acc[i][j][1] + b4.y;
      o.z = acc[i][j][2] + b4.z; o.w = acc[i][j][3] + b4.w;
      *(float4*)(out + (size_t)m * DIMM + jc0) = o;
    }
  }
}

// ---------------------------------------------------------------------------
extern "C" void kernel_launch(void* const* d_in, const int* in_sizes, int n_in,
                              void* d_out, int out_size, void* d_ws, size_t ws_size,
                              hipStream_t stream) {
  const float* x     = (const float*)d_in[0];
  const float* wqkv  = (const float*)d_in[1];
  const float* wproj = (const float*)d_in[2];
  const float* bproj = (const float*)d_in[3];

  char* ws = (char*)d_ws;
  uint16_t* xb  = (uint16_t*)(ws + 0);          //  8,388,608  x bf16 [8192][512]
  uint16_t* wqb = (uint16_t*)(ws + 8388608);    //  1,572,864  w_qkv bf16 [1536][512]
  uint16_t* wpb = (uint16_t*)(ws + 9961472);    //    524,288  w_proj bf16 [512][512]
  uint16_t* qd  = (uint16_t*)(ws + 10485760);   //  8,388,608  q bf16 [16][4096][64] (scaled)
  uint16_t* kd  = (uint16_t*)(ws + 18874368);   //  8,388,608  k bf16 [16][4096][64]
  uint16_t* vt  = (uint16_t*)(ws + 27262976);   //  8,388,608  v bf16 [16][64][4096]
  uint16_t* ao  = (uint16_t*)(ws + 35651584);   //  8,388,608  attn out bf16 [8192][512]

  cvt_kernel<<<(X4 + Q4 + P4) / 256, 256, 0, stream>>>(x, wqkv, wproj, xb, wqb, wpb);
  qk_gemm<<<dim3(8, 64), 256, 0, stream>>>(xb, wqb, qd, kd);
  v_gemm<<<dim3(64, 4), 256, 0, stream>>>(xb, wqb + 1024 * DIMM, vt);
  attn_kernel<<<512, 512, 0, stream>>>(qd, kd, vt, ao);
  proj_gemm<<<dim3(4, 64), 256, 0, stream>>>(ao, wpb, bproj, (float*)d_out);
}

// Round 9
// 202.401 us; speedup vs baseline: 1.2223x; 1.2223x over previous
//
#include <hip/hip_runtime.h>
#include <stdint.h>

// Problem constants
#define SEQ   4096
#define DIMM  512
#define HDIM  64
#define NH    8
#define ROWS  8192          // B*N = 2*4096
#define QKVN  1536          // 3*DIM

typedef __attribute__((ext_vector_type(8))) __bf16 bf16x8;   // MFMA A/B frag (4 VGPRs)
typedef __attribute__((ext_vector_type(4))) float  f32x4;    // MFMA C/D frag
typedef __attribute__((ext_vector_type(2))) uint32_t u32x2;

// fp32 -> bf16 (RNE), storage as uint16_t bit pattern
__device__ __forceinline__ uint16_t f2bfu(float f) {
  uint32_t u = __builtin_bit_cast(uint32_t, f);
  return (uint16_t)((u + 0x7FFFu + ((u >> 16) & 1u)) >> 16);
}

__device__ __forceinline__ f32x4 mfma16(bf16x8 a, bf16x8 b, f32x4 c) {
  return __builtin_amdgcn_mfma_f32_16x16x32_bf16(a, b, c, 0, 0, 0);
}

#if __has_builtin(__builtin_amdgcn_exp2f)
#define EXP2F(x) __builtin_amdgcn_exp2f(x)
#else
#define EXP2F(x) exp2f(x)
#endif

// async global->LDS, 16B per lane. LDS dest is wave-uniform base + lane*16;
// the GLOBAL address is per-lane free -> we use it to store XOR-swizzled tiles.
__device__ __forceinline__ void gld16(const void* g, void* l) {
  __builtin_amdgcn_global_load_lds(
      (const __attribute__((address_space(1))) uint32_t*)g,
      (__attribute__((address_space(3))) uint32_t*)l, 16, 0, 0);
}

// ---------------------------------------------------------------------------
// Kernel 1: fp32 -> bf16 conversion of x, w_qkv, w_proj (one grid, 3 segments)
// ---------------------------------------------------------------------------
#define X4  (ROWS * DIMM / 4)    // 1048576
#define Q4  (QKVN * DIMM / 4)    // 196608
#define P4  (DIMM * DIMM / 4)    // 65536

__global__ __launch_bounds__(256) void cvt_kernel(
    const float* __restrict__ x, const float* __restrict__ wq,
    const float* __restrict__ wp, uint16_t* __restrict__ xb,
    uint16_t* __restrict__ wqb, uint16_t* __restrict__ wpb) {
  int idx = blockIdx.x * 256 + threadIdx.x;    // float4 index
  const float* src; uint16_t* dst; int i4;
  if (idx < X4)            { src = x;  dst = xb;  i4 = idx; }
  else if (idx < X4 + Q4)  { src = wq; dst = wqb; i4 = idx - X4; }
  else                     { src = wp; dst = wpb; i4 = idx - X4 - Q4; }
  float4 v = ((const float4*)src)[i4];
  ushort4 o;
  o.x = f2bfu(v.x); o.y = f2bfu(v.y); o.z = f2bfu(v.z); o.w = f2bfu(v.w);
  ((ushort4*)dst)[i4] = o;
}

// ---------------------------------------------------------------------------
// Shared GEMM core: C[128x128] = A[128xK] * B[128xK]^T  (both row-major, K=512)
// 256 threads = 4 waves in 2x2, each wave 64x64 via 4x4 MFMA frags.
// acc[i][j] frag: C[row = A-row][col = B-row]. Orientation (C vs C^T) is chosen
// by which operand is passed as A.
// ---------------------------------------------------------------------------
__device__ __forceinline__ void gemm_core(
    const uint16_t* __restrict__ A, const uint16_t* __restrict__ B,
    uint16_t* As, uint16_t* Bs, f32x4 acc[4][4]) {
  const int tid = threadIdx.x;
  const int lane = tid & 63, wave = tid >> 6;
  const int quad = lane >> 4, l16 = lane & 15;
  const int wr = (wave & 1) * 64, wc = (wave >> 1) * 64;
  const int bm = blockIdx.x, bn = blockIdx.y;
  const int sw = (l16 >> 1) & 3;               // read-side swizzle key

  for (int kt = 0; kt < DIMM / 32; ++kt) {
#pragma unroll
    for (int it = 0; it < 2; ++it) {
      int L = it * 256 + tid;
      int r = L >> 2, c = L & 3;
      int gc = c ^ ((r >> 1) & 3);
      int ldsoff = (it * 256 + (tid & ~63)) * 16; // wave-uniform base
      gld16((const char*)A + ((size_t)(bm * 128 + r) * DIMM + kt * 32) * 2 + gc * 16,
            (char*)As + ldsoff);
      gld16((const char*)B + ((size_t)(bn * 128 + r) * DIMM + kt * 32) * 2 + gc * 16,
            (char*)Bs + ldsoff);
    }
    __syncthreads();
    bf16x8 af[4], bfr[4];
#pragma unroll
    for (int i = 0; i < 4; ++i)
      af[i] = *(const bf16x8*)(As + (wr + i * 16 + l16) * 32 + ((quad ^ sw) * 8));
#pragma unroll
    for (int j = 0; j < 4; ++j)
      bfr[j] = *(const bf16x8*)(Bs + (wc + j * 16 + l16) * 32 + ((quad ^ sw) * 8));
#pragma unroll
    for (int i = 0; i < 4; ++i)
#pragma unroll
      for (int j = 0; j < 4; ++j)
        acc[i][j] = mfma16(af[i], bfr[j], acc[i][j]);
    __syncthreads();
  }
}

// ---------------------------------------------------------------------------
// Kernel 2a: QK GEMM in C^T orientation: C^T[jc][m] = W_qk · X^T.
// Lane's 4 acc regs = 4 consecutive jc (= consecutive hd) -> ushort4 stores.
//   q: [bh][n][64] bf16, pre-scaled by 0.125*log2(e); k: [bh][n][64] bf16
// Grid (8, 64): bm over jc-tiles (rows 0..1023 of w_qkv), bn over m-tiles.
// ---------------------------------------------------------------------------
__global__ __launch_bounds__(256, 2) void qk_gemm(
    const uint16_t* __restrict__ xb, const uint16_t* __restrict__ wqb,
    uint16_t* __restrict__ qd, uint16_t* __restrict__ kd) {
  __shared__ __align__(16) uint16_t As[128 * 32];
  __shared__ __align__(16) uint16_t Bs[128 * 32];
  f32x4 acc[4][4];
#pragma unroll
  for (int i = 0; i < 4; ++i)
#pragma unroll
    for (int j = 0; j < 4; ++j) acc[i][j] = f32x4{0.f, 0.f, 0.f, 0.f};

  gemm_core(wqb, xb, As, Bs, acc);    // A = weights -> acc rows are jc

  const int lane = threadIdx.x & 63, wave = threadIdx.x >> 6;
  const int quad = lane >> 4, l16 = lane & 15;
  const int wr = (wave & 1) * 64, wc = (wave >> 1) * 64;
  const float qscale = 0.125f * 1.44269504f;   // fold log2(e) for exp2 softmax
  const bool isq = (blockIdx.x < 4);           // jc < 512 -> q (uniform per block)
  uint16_t* dst = isq ? qd : kd;
  const float s = isq ? qscale : 1.0f;
#pragma unroll
  for (int i = 0; i < 4; ++i) {
    int jc0 = blockIdx.x * 128 + wr + i * 16 + quad * 4;  // 4 consecutive jc
    int h = (jc0 >> 6) & 7, hd = jc0 & 63;                // hd % 4 == 0
#pragma unroll
    for (int j = 0; j < 4; ++j) {
      int m = blockIdx.y * 128 + wc + j * 16 + l16;
      int b = m >> 12, n = m & 4095;
      int bh = (b << 3) | h;
      ushort4 pk;
      pk.x = f2bfu(acc[i][j][0] * s); pk.y = f2bfu(acc[i][j][1] * s);
      pk.z = f2bfu(acc[i][j][2] * s); pk.w = f2bfu(acc[i][j][3] * s);
      *(ushort4*)(dst + ((size_t)bh * SEQ + n) * HDIM + hd) = pk;
    }
  }
}

// ---------------------------------------------------------------------------
// Kernel 2b: V GEMM, normal orientation (lane's 4 regs = 4 consecutive n ->
// ushort4 into transposed vt). Grid (64, 4): bm over m, bn over v-cols.
//   v: stored TRANSPOSED [bh][64][n] bf16
// ---------------------------------------------------------------------------
__global__ __launch_bounds__(256, 2) void v_gemm(
    const uint16_t* __restrict__ xb, const uint16_t* __restrict__ wvb,
    uint16_t* __restrict__ vt) {
  __shared__ __align__(16) uint16_t As[128 * 32];
  __shared__ __align__(16) uint16_t Bs[128 * 32];
  f32x4 acc[4][4];
#pragma unroll
  for (int i = 0; i < 4; ++i)
#pragma unroll
    for (int j = 0; j < 4; ++j) acc[i][j] = f32x4{0.f, 0.f, 0.f, 0.f};

  gemm_core(xb, wvb, As, Bs, acc);    // A = x -> acc rows are m

  const int lane = threadIdx.x & 63, wave = threadIdx.x >> 6;
  const int quad = lane >> 4, l16 = lane & 15;
  const int wr = (wave & 1) * 64, wc = (wave >> 1) * 64;
#pragma unroll
  for (int i = 0; i < 4; ++i) {
    int m0 = blockIdx.x * 128 + wr + i * 16 + quad * 4;  // 4 consecutive n
    int b = m0 >> 12, n0 = m0 & 4095;
#pragma unroll
    for (int j = 0; j < 4; ++j) {
      int jcl = blockIdx.y * 128 + wc + j * 16 + l16;    // 0..511 within v region
      int h = (jcl >> 6) & 7, hd = jcl & 63;
      int bh = (b << 3) | h;
      ushort4 pk;
      pk.x = f2bfu(acc[i][j][0]); pk.y = f2bfu(acc[i][j][1]);
      pk.z = f2bfu(acc[i][j][2]); pk.w = f2bfu(acc[i][j][3]);
      *(ushort4*)(vt + ((size_t)bh * HDIM + hd) * SEQ + n0) = pk;
    }
  }
}

// ---------------------------------------------------------------------------
// Kernel 3: flash attention, S^T formulation, key-split wave pairs (R7 core)
// + R8's XCD-local 1D grid: bh = blk & 15, qt = blk >> 4 -> all 32 blocks of
// a bh land on one XCD (blk%8 == bh%8); 2 bh/XCD ~ 3MB < 4MB L2, so staging
// DMA + barrier drains hit XCD-local L2 instead of L3/HBM.
// 512 threads = 8 waves; pair = wave>>1 owns 32 q-rows; khalf = wave&1 takes
// 64 of each 128-key tile. K/V staged via gld16 (latency paid once per
// barrier for all waves -- R8 proved per-lane global K on the MFMA chain
// stalls everything).
// LDS = Ks 16K + Vs 16K + Ps 8x4K = 64KB; 2 blocks/CU -> 16 waves/CU.
// ---------------------------------------------------------------------------
__global__ __launch_bounds__(512, 4) void attn_kernel(
    const uint16_t* __restrict__ qd, const uint16_t* __restrict__ kd,
    const uint16_t* __restrict__ vt, uint16_t* __restrict__ ao) {
  __shared__ __align__(16) uint16_t Ks[128 * 64];    // [key][d], chunk c^=(row&7)
  __shared__ __align__(16) uint16_t Vs[64 * 128];    // [d][key], chunk c^=(row&15)
  __shared__ __align__(16) uint16_t Ps[8][32 * 64];  // per-wave [q32][key64], 4KB each

  const int tid = threadIdx.x, lane = tid & 63, wave = tid >> 6;  // wave 0..7
  const int quad = lane >> 4, l16 = lane & 15;
  const int pair = wave >> 1, khalf = wave & 1;
  const int qt = blockIdx.x >> 4, bh = blockIdx.x & 15;   // XCD-local bh
  const size_t base_qk = (size_t)bh * SEQ * HDIM;    // [bh][n][d]
  const size_t base_v  = (size_t)bh * HDIM * SEQ;    // [bh][d][n]
  const int sw7 = l16 & 7;
  char* Pw = (char*)Ps + wave * 4096;

  // Q fragments straight from global (one-time, L2-resident): B-op of K·Q^T
  bf16x8 qf[2][2];
#pragma unroll
  for (int it2 = 0; it2 < 2; ++it2)
#pragma unroll
    for (int kh = 0; kh < 2; ++kh)
      qf[it2][kh] = *(const bf16x8*)(qd + base_qk +
          (size_t)(qt * 128 + pair * 32 + it2 * 16 + l16) * HDIM + kh * 32 + quad * 8);

  f32x4 O[2][4];            // partial over this wave's keys
  float lsum[2] = {0.f, 0.f};
#pragma unroll
  for (int a = 0; a < 2; ++a)
#pragma unroll
    for (int d = 0; d < 4; ++d) O[a][d] = f32x4{0.f, 0.f, 0.f, 0.f};

  for (int kt = 0; kt < SEQ / 128; ++kt) {
    // stage K [128][64] and Vt [64][128], both chunk-swizzled (512 thr, 2 iters)
#pragma unroll
    for (int it = 0; it < 2; ++it) {
      int L = it * 512 + tid;
      int ldsoff = (it * 512 + (tid & ~63)) * 16;
      int rk = L >> 3, ck = L & 7;
      int gck = ck ^ (rk & 7);
      gld16((const char*)kd + (base_qk + (size_t)(kt * 128 + rk) * HDIM) * 2 + gck * 16,
            (char*)Ks + ldsoff);
      int rv = L >> 4, cv = L & 15;
      int gcv = cv ^ (rv & 15);
      gld16((const char*)vt + (base_v + (size_t)rv * SEQ + (size_t)kt * 128) * 2 + gcv * 16,
            (char*)Vs + ldsoff);
    }
    __syncthreads();

    // S^T = K·Q^T for this wave's 64 keys (4 key-16-blocks)
    f32x4 P[4][2];
#pragma unroll
    for (int jh = 0; jh < 4; ++jh) {
      int jf = khalf * 4 + jh;
      const uint16_t* krow = Ks + (jf * 16 + l16) * 64;
      bf16x8 kf0 = *(const bf16x8*)(krow + ((quad ^ sw7) * 8));
      bf16x8 kf1 = *(const bf16x8*)(krow + (((4 + quad) ^ sw7) * 8));
#pragma unroll
      for (int it2 = 0; it2 < 2; ++it2) {
        f32x4 s = f32x4{0.f, 0.f, 0.f, 0.f};
        s = mfma16(kf0, qf[it2][0], s);
        s = mfma16(kf1, qf[it2][1], s);
        P[jh][it2] = s;
      }
    }

    // exp2, per-lane l partials, pack 4 consecutive keys -> one b64 LDS write
#pragma unroll
    for (int jh = 0; jh < 4; ++jh)
#pragma unroll
      for (int it2 = 0; it2 < 2; ++it2) {
        float p0 = EXP2F(P[jh][it2][0]);
        float p1 = EXP2F(P[jh][it2][1]);
        float p2 = EXP2F(P[jh][it2][2]);
        float p3 = EXP2F(P[jh][it2][3]);
        lsum[it2] += (p0 + p1) + (p2 + p3);
        uint32_t a0 = __builtin_bit_cast(uint32_t, p0) + 0x8000u;
        uint32_t a1 = __builtin_bit_cast(uint32_t, p1) + 0x8000u;
        uint32_t a2 = __builtin_bit_cast(uint32_t, p2) + 0x8000u;
        uint32_t a3 = __builtin_bit_cast(uint32_t, p3) + 0x8000u;
        u32x2 pk;
        pk.x = (a0 >> 16) | (a1 & 0xFFFF0000u);   // [bf16(p0), bf16(p1)]
        pk.y = (a2 >> 16) | (a3 & 0xFFFF0000u);   // [bf16(p2), bf16(p3)]
        int c16 = (jh * 2 + (quad >> 1)) ^ sw7;
        *(u32x2*)(Pw + (it2 * 16 + l16) * 128 + c16 * 16 + (quad & 1) * 8) = pk;
      }

    // O^T += V^T·P^T over this wave's 64 keys (2 blocks of K=32)
#pragma unroll
    for (int kp = 0; kp < 2; ++kp) {
      bf16x8 pb[2];
#pragma unroll
      for (int it2 = 0; it2 < 2; ++it2)
        pb[it2] = *(const bf16x8*)(Pw + (it2 * 16 + l16) * 128 +
                                   (((kp * 4 + quad) ^ sw7) * 16));
      bf16x8 va[4];
#pragma unroll
      for (int dl = 0; dl < 4; ++dl)
        va[dl] = *(const bf16x8*)((const char*)Vs + (dl * 16 + l16) * 256 +
                                  (((khalf * 8 + kp * 4 + quad) ^ l16) & 15) * 16);
#pragma unroll
      for (int it2 = 0; it2 < 2; ++it2)
#pragma unroll
        for (int dl = 0; dl < 4; ++dl)
          O[it2][dl] = mfma16(va[dl], pb[it2], O[it2][dl]);
    }
    __syncthreads();
  }

  // merge partial O / lsum across the wave pair (even wave -> LDS, odd reads)
  if (!(wave & 1)) {
    f32x4* ob = (f32x4*)((char*)Ps + wave * 4096);   // 8KB: Ps[wave]+Ps[wave+1]
#pragma unroll
    for (int it2 = 0; it2 < 2; ++it2)
#pragma unroll
      for (int dl = 0; dl < 4; ++dl)
        ob[(it2 * 4 + dl) * 64 + lane] = O[it2][dl];
    float2* lb = (float2*)((char*)Ks + pair * 512);
    lb[lane] = make_float2(lsum[0], lsum[1]);
  }
  __syncthreads();
  if (wave & 1) {
    const f32x4* ob = (const f32x4*)((char*)Ps + (wave - 1) * 4096);
    float2 lp = ((const float2*)((char*)Ks + pair * 512))[lane];
    lsum[0] += lp.x; lsum[1] += lp.y;
#pragma unroll
    for (int it2 = 0; it2 < 2; ++it2)
#pragma unroll
      for (int dl = 0; dl < 4; ++dl)
        O[it2][dl] += ob[(it2 * 4 + dl) * 64 + lane];

    const int b = bh >> 3, h = bh & 7;
#pragma unroll
    for (int it2 = 0; it2 < 2; ++it2) {
      float l = lsum[it2];
      l += __shfl_xor(l, 16);
      l += __shfl_xor(l, 32);
      float inv = 1.0f / l;
      int q = qt * 128 + pair * 32 + it2 * 16 + l16;
      size_t rowbase = ((size_t)(b * SEQ + q)) * DIMM + h * HDIM;
#pragma unroll
      for (int dl = 0; dl < 4; ++dl) {
        ushort4 pk;
        pk.x = f2bfu(O[it2][dl][0] * inv);
        pk.y = f2bfu(O[it2][dl][1] * inv);
        pk.z = f2bfu(O[it2][dl][2] * inv);
        pk.w = f2bfu(O[it2][dl][3] * inv);
        *(ushort4*)(ao + rowbase + dl * 16 + quad * 4) = pk;
      }
    }
  }
}

// ---------------------------------------------------------------------------
// Kernel 4: output projection in C^T orientation: C^T[jc][m] = W_p · AO^T.
// Lane's 4 regs = 4 consecutive out-cols -> float4 store with float4 bias.
// Grid (4, 64).
// ---------------------------------------------------------------------------
__global__ __launch_bounds__(256, 2) void proj_gemm(
    const uint16_t* __restrict__ ao, const uint16_t* __restrict__ wpb,
    const float* __restrict__ bprj, float* __restrict__ out) {
  __shared__ __align__(16) uint16_t As[128 * 32];
  __shared__ __align__(16) uint16_t Bs[128 * 32];
  f32x4 acc[4][4];
#pragma unroll
  for (int i = 0; i < 4; ++i)
#pragma unroll
    for (int j = 0; j < 4; ++j) acc[i][j] = f32x4{0.f, 0.f, 0.f, 0.f};

  gemm_core(wpb, ao, As, Bs, acc);    // A = weights -> acc rows are jc

  const int lane = threadIdx.x & 63, wave = threadIdx.x >> 6;
  const int quad = lane >> 4, l16 = lane & 15;
  const int wr = (wave & 1) * 64, wc = (wave >> 1) * 64;
#pragma unroll
  for (int i = 0; i < 4; ++i) {
    int jc0 = blockIdx.x * 128 + wr + i * 16 + quad * 4;  // 4 consecutive cols
    float4 b4 = *(const float4*)(bprj + jc0);
#pragma unroll
    for (int j = 0; j < 4; ++j) {
      int m = blockIdx.y * 128 + wc + j * 16 + l16;
      float4 o;
      o.x = acc[i][j][0] + b4.x; o.y = acc[i][j][1] + b4.y;
      o.z = acc[i][j][2] + b4.z; o.w = acc[i][j][3] + b4.w;
      *(float4*)(out + (size_t)m * DIMM + jc0) = o;
    }
  }
}

// ---------------------------------------------------------------------------
extern "C" void kernel_launch(void* const* d_in, const int* in_sizes, int n_in,
                              void* d_out, int out_size, void* d_ws, size_t ws_size,
                              hipStream_t stream) {
  const float* x     = (const float*)d_in[0];
  const float* wqkv  = (const float*)d_in[1];
  const float* wproj = (const float*)d_in[2];
  const float* bproj = (const float*)d_in[3];

  char* ws = (char*)d_ws;
  uint16_t* xb  = (uint16_t*)(ws + 0);          //  8,388,608  x bf16 [8192][512]
  uint16_t* wqb = (uint16_t*)(ws + 8388608);    //  1,572,864  w_qkv bf16 [1536][512]
  uint16_t* wpb = (uint16_t*)(ws + 9961472);    //    524,288  w_proj bf16 [512][512]
  uint16_t* qd  = (uint16_t*)(ws + 10485760);   //  8,388,608  q bf16 [16][4096][64] (scaled)
  uint16_t* kd  = (uint16_t*)(ws + 18874368);   //  8,388,608  k bf16 [16][4096][64]
  uint16_t* vt  = (uint16_t*)(ws + 27262976);   //  8,388,608  v bf16 [16][64][4096]
  uint16_t* ao  = (uint16_t*)(ws + 35651584);   //  8,388,608  attn out bf16 [8192][512]

  cvt_kernel<<<(X4 + Q4 + P4) / 256, 256, 0, stream>>>(x, wqkv, wproj, xb, wqb, wpb);
  qk_gemm<<<dim3(8, 64), 256, 0, stream>>>(xb, wqb, qd, kd);
  v_gemm<<<dim3(64, 4), 256, 0, stream>>>(xb, wqb + 1024 * DIMM, vt);
  attn_kernel<<<512, 512, 0, stream>>>(qd, kd, vt, ao);
  proj_gemm<<<dim3(4, 64), 256, 0, stream>>>(ao, wpb, bproj, (float*)d_out);
}